// Round 9
// baseline (195.680 us; speedup 1.0000x reference)
//
#include <hip/hip_runtime.h>
#include <hip/hip_fp16.h>

#define LATENT 64
#define N_USERS_C 100000

#define BROWS 64
#define LOG_BROWS 6
#define NBUCK_MAX 2368         // >= ceil(150000/64) = 2344
#define NBLKA_MAX 512          // >= ceil(nnz/4096) = 293
#define SORT_T 256
#define SORT_E 16
#define SORT_CHUNK (SORT_T * SORT_E)   // 4096 edges per block
#define BUCK_CAP 1536          // max edges per 64-row bucket (mult of 4)

typedef unsigned short ushort8_t __attribute__((ext_vector_type(8)));

// Edge payload: col:18 | val-e4m10:14  (exp bias 0x77 -> covers 2^-8..2^7;
// vals in [0.022, 1.0]; enc==0 reserved for "zero weight").
__device__ __forceinline__ unsigned enc_val14(float v) {
    unsigned vb = (unsigned)__float_as_int(v) + 0x1000u;            // round to nearest
    return (((vb >> 23) - 0x77u) << 10) | ((vb >> 13) & 0x3FFu);    // 14 bits
}
__device__ __forceinline__ float dec_val14(unsigned m) {
    return __uint_as_float(m ? ((((m >> 10) + 0x77u) << 23) | ((m & 0x3FFu) << 13)) : 0u);
}

// ---- shfl-based scans ----
__device__ __forceinline__ int wave_iscan(int x, int lane) {
#pragma unroll
    for (int o = 1; o < 64; o <<= 1) {
        int y = __shfl_up(x, o, 64);
        if (lane >= o) x += y;
    }
    return x;   // inclusive within 64-lane wave
}
// exclusive scan of v over the 256-thread block; ws = __shared__ int[4]; *tot = grand total
__device__ __forceinline__ int block_escan(int v, int* ws, int* tot) {
    int t = threadIdx.x, lane = t & 63, w = t >> 6;
    int inc = wave_iscan(v, lane);
    __syncthreads();                 // protect ws reuse across consecutive calls
    if (lane == 63) ws[w] = inc;
    __syncthreads();
    int s0 = ws[0], s1 = ws[1], s2 = ws[2], s3 = ws[3];
    *tot = s0 + s1 + s2 + s3;
    int base = (w > 0 ? s0 : 0) + (w > 1 ? s1 : 0) + (w > 2 ? s2 : 0);
    return base + inc - v;
}

// m204 bijective XCD-contiguous swizzle WITHIN a segment of size n.
__device__ __forceinline__ int swz_seg(int i, int n) {
    const int NX = 8;
    int q = n / NX, r = n % NX;
    int x = i % NX, o = i / NX;
    return (x < r ? x * (q + 1) : r * (q + 1) + (x - r) * q) + o;
}

// ---------- Phase A: per-block LDS bucket sort (blocks [0,nblkA)) fused with
// ---------- fp32->fp16 table conversion (blocks [nblkA, ...)) ----------
// csmat is BLK-MAJOR (coalesced-ish writes, fused into the scan sweep).

__global__ void sortA_conv_kernel(const int* __restrict__ row, const int* __restrict__ col,
                                  const float* __restrict__ vals,
                                  unsigned* __restrict__ aux, unsigned char* __restrict__ rowloc,
                                  unsigned* __restrict__ csmat,
                                  int* __restrict__ bcnt, int nnz, int nbuck, int nblkA,
                                  const float* __restrict__ E0, __half* __restrict__ E0h,
                                  int n4) {
    __shared__ int cnt[NBUCK_MAX];
    __shared__ int off[NBUCK_MAX];
    __shared__ int ws[4];
    __shared__ unsigned buf[SORT_CHUNK];        // 16 KB
    __shared__ unsigned char rbuf[SORT_CHUNK];  // 4 KB
    int t = threadIdx.x;

    if (blockIdx.x >= nblkA) {
        // ---- conversion blocks: 4 float4 per thread, coalesced ----
        int cb = blockIdx.x - nblkA;
        int base4 = cb * (SORT_T * 4);
#pragma unroll
        for (int jj = 0; jj < 4; jj++) {
            int i = base4 + jj * SORT_T + t;
            if (i < n4) {
                float4 v = ((const float4*)E0)[i];
                __half2* o = (__half2*)E0h;
                o[2 * i]     = __floats2half2_rn(v.x, v.y);
                o[2 * i + 1] = __floats2half2_rn(v.z, v.w);
            }
        }
        return;
    }

    int blk = blockIdx.x;
    int base = blk * SORT_CHUNK;

    for (int i = t; i < nbuck; i += SORT_T) cnt[i] = 0;
    __syncthreads();

    int      eb[SORT_E];
    unsigned pl[SORT_E];
    unsigned char rl8[SORT_E];
    int quadbase = base >> 2;
#pragma unroll
    for (int jq = 0; jq < SORT_E / 4; jq++) {
        int q = quadbase + jq * SORT_T + t;      // quad index (4 edges)
        int e0 = 4 * q;
        if (e0 + 3 < nnz) {
            int4   r4 = ((const int4*)row)[q];
            int4   c4 = ((const int4*)col)[q];
            float4 v4 = ((const float4*)vals)[q];
            int   rr[4] = { r4.x, r4.y, r4.z, r4.w };
            int   cc[4] = { c4.x, c4.y, c4.z, c4.w };
            float vv[4] = { v4.x, v4.y, v4.z, v4.w };
#pragma unroll
            for (int jj = 0; jj < 4; jj++) {
                int j = 4 * jq + jj;
                int r = rr[jj];
                int b = r >> LOG_BROWS;
                eb[j] = b;
                pl[j] = (unsigned)cc[jj] | (enc_val14(vv[jj]) << 18);
                rl8[j] = (unsigned char)(r & (BROWS - 1));
                atomicAdd(&cnt[b], 1);
            }
        } else {
#pragma unroll
            for (int jj = 0; jj < 4; jj++) {
                int j = 4 * jq + jj;
                int e = e0 + jj;
                if (e < nnz) {
                    int r = row[e];
                    int b = r >> LOG_BROWS;
                    eb[j] = b;
                    pl[j] = (unsigned)col[e] | (enc_val14(vals[e]) << 18);
                    rl8[j] = (unsigned char)(r & (BROWS - 1));
                    atomicAdd(&cnt[b], 1);
                } else {
                    eb[j] = -1;
                }
            }
        }
    }
    __syncthreads();

    // scan sweep fused with csmat write + bcnt atomic (beg == pre-placement run)
    int chunk = (nbuck + SORT_T - 1) / SORT_T;
    int lo = t * chunk, hi = lo + chunk; if (hi > nbuck) hi = nbuck;
    int s = 0;
    for (int i = lo; i < hi; i++) s += cnt[i];
    int tot_;
    int run = block_escan(s, ws, &tot_);
    for (int i = lo; i < hi; i++) {
        int c = cnt[i];
        off[i] = run;
        csmat[(size_t)blk * nbuck + i] = ((unsigned)run << 16) | (unsigned)c;
        if (c) atomicAdd(&bcnt[i], c);
        run += c;
    }
    __syncthreads();

#pragma unroll
    for (int j = 0; j < SORT_E; j++) {
        if (eb[j] >= 0) {
            int p = atomicAdd(&off[eb[j]], 1);
            buf[p] = pl[j];
            rbuf[p] = rl8[j];
        }
    }
    __syncthreads();

    int nvalid = nnz - base; if (nvalid > SORT_CHUNK) nvalid = SORT_CHUNK;
    for (int i = t; i < nvalid; i += SORT_T) {
        aux[base + i] = buf[i];
        rowloc[base + i] = rbuf[i];
    }
}

// ---------- Phase B: bucket -> degree-sorted-slot CSR, FUSED with layer-1 SpMM ----
// Two-segment XCD swizzle (R8). New in R9: (a) placed edges also kept in LDS
// (plbuf) so the fused spmm's edge fetch is a ds_read, not an L2 round-trip on
// the critical path; (b) degree-SPREAD wave mapping (sl = wv + 4*g) so each
// wave gets an even slice of the degree spectrum (kills the wave-3 straggler).

__global__ void sortB_spmm1_kernel(const unsigned* __restrict__ aux,
                                   const unsigned char* __restrict__ rowloc,
                                   const unsigned* __restrict__ csmat,
                                   const int* __restrict__ bcnt,
                                   unsigned* __restrict__ edges, int* __restrict__ startOut,
                                   int* __restrict__ origRow, int* __restrict__ slotOfRow,
                                   const __half* __restrict__ E0h, __half* __restrict__ E1,
                                   int nblkA, int nbuck, int ntotal, int nnz) {
    __shared__ int rs[NBLKA_MAX], roff[NBLKA_MAX + 1];
    __shared__ int ws[4];
    __shared__ unsigned buf[BUCK_CAP];          // 6 KB (gather order)
    __shared__ unsigned plbuf[BUCK_CAP];        // 6 KB (placed order, spmm source)
    __shared__ unsigned char rbuf[BUCK_CAP];    // 1.5 KB
    __shared__ int cnt64[BROWS];
    __shared__ int slotOf[BROWS];
    __shared__ int rowOf[BROWS];
    __shared__ int offS[BROWS];
    __shared__ int placeOff[BROWS];
    __shared__ int dhist[64];
    int t = threadIdx.x;
    int lane = t & 63;

    // two-segment bijective swizzle: user segment [0,nbU), item segment [nbU,nbuck)
    int blk = blockIdx.x;
    const int nbU = (N_USERS_C + BROWS - 1) >> LOG_BROWS;   // 1563
    int b = (blk < nbU) ? swz_seg(blk, nbU)
                        : nbU + swz_seg(blk - nbU, nbuck - nbU);

    // ---- base = sum(bcnt[0..b)) via strided partials + block reduce ----
    int sb = 0;
    for (int i = t; i < b; i += SORT_T) sb += bcnt[i];
    int base;
    (void)block_escan(sb, ws, &base);      // total of partials = base

    int rbase = b * BROWS;
    int nr = ntotal - rbase; if (nr > BROWS) nr = BROWS;

    // ---- column read of blk-major csmat (L2-shared across same-XCD buckets) ----
    int chunk = (nblkA + SORT_T - 1) / SORT_T;   // 2
    int lo = t * chunk, hi = lo + chunk; if (hi > nblkA) hi = nblkA;
    int rcl[2];
    int s = 0;
    for (int i = lo; i < hi; i++) {
        unsigned v = csmat[(size_t)i * nbuck + b];
        int c = (int)(v & 0xFFFFu);
        rcl[i - lo] = c;
        rs[i] = (int)(v >> 16);
        s += c;
    }
    if (t < BROWS) cnt64[t] = 0;
    if (t < 64) dhist[t] = 0;
    int tot;                                  // bucket total = sum of chunk counts
    int run = block_escan(s, ws, &tot);
    for (int i = lo; i < hi; i++) { roff[i] = run; run += rcl[i - lo]; }
    if (t == 0) roff[nblkA] = tot;
    __syncthreads();

    // coalesced gather: edge i -> binary search run (largest with roff[r] <= i)
    for (int i = t; i < tot; i += SORT_T) {
        int lo2 = 0, hi2 = nblkA;
        while (hi2 - lo2 > 1) {
            int mid = (lo2 + hi2) >> 1;
            if (roff[mid] <= i) lo2 = mid; else hi2 = mid;
        }
        size_t src = (size_t)lo2 * SORT_CHUNK + rs[lo2] + (i - roff[lo2]);
        buf[i] = aux[src];
        unsigned char rl = rowloc[src];
        rbuf[i] = rl;
        atomicAdd(&cnt64[rl], 1);
    }
    __syncthreads();

    // ---- degree-sorted slot assignment (single-wave shfl scans) ----
    if (t < nr) { int d = min(cnt64[t], 63); atomicAdd(&dhist[d], 1); }
    __syncthreads();
    if (t < 64) {
        int x = dhist[lane];
        int inc = wave_iscan(x, lane);
        dhist[lane] = inc - x;           // exclusive
    }
    __syncthreads();
    if (t < nr) {
        int d = min(cnt64[t], 63);
        int sl = atomicAdd(&dhist[d], 1);
        slotOf[t] = sl;
        rowOf[sl] = t;
    }
    __syncthreads();
    if (t < 64) {
        int x = (lane < nr) ? cnt64[rowOf[lane]] : 0;
        int inc = wave_iscan(x, lane);
        offS[lane] = inc - x;            // exclusive
    }
    __syncthreads();

    if (t < nr) {
        startOut[rbase + t]   = base + offS[t];
        origRow[rbase + t]    = rbase + rowOf[t];
        slotOfRow[rbase + t]  = rbase + slotOf[t];   // row -> global slot (for fused L3)
        placeOff[t] = offS[slotOf[t]];
    }
    if (b == nbuck - 1 && t == 0) startOut[ntotal] = nnz;
    __syncthreads();

    // placement: fill LDS plbuf (spmm source) + global edges (layer2/fin source)
    for (int i = t; i < tot; i += SORT_T) {
        int p = atomicAdd(&placeOff[rbuf[i]], 1);
        unsigned pay = buf[i];
        plbuf[p] = pay;
        edges[base + p] = pay;
    }
    __syncthreads();   // plbuf + edges visible in-block

    // ---- fused layer-1 SpMM over this bucket's degree-sorted slots ----
    // 8 lanes x 8 dims per slot; degree-spread mapping sl = wv + 4*g (+32n)
    // balances total edge load across the block's 4 waves.
    {
        int wv = t >> 6;
        int g = lane >> 3, l = lane & 7;
        for (int sl = wv + 4 * g; sl < nr; sl += 32) {
            int lb = offS[sl];
            int le = lb + cnt64[rowOf[sl]];
            int ro = rbase + rowOf[sl];
            float a0 = 0.f, a1 = 0.f, a2 = 0.f, a3 = 0.f;
            float a4 = 0.f, a5 = 0.f, a6 = 0.f, a7 = 0.f;
            for (int k = (lb & ~3); k < le; k += 4) {
                uint4 ev = *(const uint4*)&plbuf[k];   // LDS ds_read_b128
                unsigned ed[4] = { ev.x, ev.y, ev.z, ev.w };
#pragma unroll
                for (int j = 0; j < 4; j++) {
                    int kk = k + j;
                    if (kk < lb || kk >= le) ed[j] = 0u;   // enc==0 -> w=0, col=0
                }
                ushort8_t gv[4];
#pragma unroll
                for (int j = 0; j < 4; j++) {
                    gv[j] = *(const ushort8_t*)(E0h + (size_t)(ed[j] & 0x3FFFFu) * LATENT + 8 * l);
                }
#pragma unroll
                for (int j = 0; j < 4; j++) {
                    float wv2 = dec_val14(ed[j] >> 18);
                    const __half2* h2 = (const __half2*)&gv[j];
                    a0 += wv2 * __low2float(h2[0]);
                    a1 += wv2 * __high2float(h2[0]);
                    a2 += wv2 * __low2float(h2[1]);
                    a3 += wv2 * __high2float(h2[1]);
                    a4 += wv2 * __low2float(h2[2]);
                    a5 += wv2 * __high2float(h2[2]);
                    a6 += wv2 * __low2float(h2[3]);
                    a7 += wv2 * __high2float(h2[3]);
                }
            }
            union { ushort8_t u; __half2 h[4]; } o;
            o.h[0] = __floats2half2_rn(a0, a1);
            o.h[1] = __floats2half2_rn(a2, a3);
            o.h[2] = __floats2half2_rn(a4, a5);
            o.h[3] = __floats2half2_rn(a6, a7);
            *(ushort8_t*)(E1 + (size_t)ro * LATENT + 8 * l) = o.u;
        }
    }
}

// ---------- SpMM over degree-sorted slots (layer 2) ----------

__global__ void spmm_slot(const int* __restrict__ start, const int* __restrict__ origRow,
                          const unsigned* __restrict__ edges,
                          const __half* __restrict__ Ein, __half* __restrict__ Eout,
                          int nslots) {
    int t = blockIdx.x * blockDim.x + threadIdx.x;
    int w = t >> 6;
    int lane = t & 63;
    int g = lane >> 3, l = lane & 7;
    int s = 8 * w + g;
    if (s >= nslots) return;
    int b = start[s];
    int e = start[s + 1];
    int ro = origRow[s];
    float a0 = 0.f, a1 = 0.f, a2 = 0.f, a3 = 0.f;
    float a4 = 0.f, a5 = 0.f, a6 = 0.f, a7 = 0.f;
    for (int k = (b & ~3); k < e; k += 4) {
        uint4 ev = *(const uint4*)(edges + k);
        unsigned ed[4] = { ev.x, ev.y, ev.z, ev.w };
#pragma unroll
        for (int j = 0; j < 4; j++) {
            int kk = k + j;
            if (kk < b || kk >= e) ed[j] = 0u;   // enc==0 -> w=0, col=0
        }
        ushort8_t gv[4];
#pragma unroll
        for (int j = 0; j < 4; j++) {
            gv[j] = *(const ushort8_t*)(Ein + (size_t)(ed[j] & 0x3FFFFu) * LATENT + 8 * l);
        }
#pragma unroll
        for (int j = 0; j < 4; j++) {
            float wv = dec_val14(ed[j] >> 18);
            const __half2* h2 = (const __half2*)&gv[j];
            a0 += wv * __low2float(h2[0]);
            a1 += wv * __high2float(h2[0]);
            a2 += wv * __low2float(h2[1]);
            a3 += wv * __high2float(h2[1]);
            a4 += wv * __low2float(h2[2]);
            a5 += wv * __high2float(h2[2]);
            a6 += wv * __low2float(h2[3]);
            a7 += wv * __high2float(h2[3]);
        }
    }
    union { ushort8_t u; __half2 h[4]; } o;
    o.h[0] = __floats2half2_rn(a0, a1);
    o.h[1] = __floats2half2_rn(a2, a3);
    o.h[2] = __floats2half2_rn(a4, a5);
    o.h[3] = __floats2half2_rn(a6, a7);
    *(ushort8_t*)(Eout + (size_t)ro * LATENT + 8 * l) = o.u;
}

// ---------- Fused layer-3 + finalize ----------

__global__ void fin_fused(const int* __restrict__ users, const int* __restrict__ pos,
                          const int* __restrict__ neg,
                          const int* __restrict__ start, const int* __restrict__ slotOfRow,
                          const unsigned* __restrict__ edges,
                          const float* __restrict__ E0, const __half* __restrict__ E1,
                          const __half* __restrict__ E2,
                          float* __restrict__ out, int batch) {
    int t = blockIdx.x * blockDim.x + threadIdx.x;
    int w = t >> 6;
    int lane = t & 63;
    int g = lane >> 4, l = lane & 15;
    int i = 4 * w + g;                  // output entry 0..3*batch
    int nent = 3 * batch;
    if (i >= nent) return;
    int grp = i / batch;
    int bb = i - grp * batch;
    int r = (grp == 0) ? users[bb] : (grp == 1) ? (N_USERS_C + pos[bb]) : (N_USERS_C + neg[bb]);
    int s = slotOfRow[r];
    int b = start[s];
    int e = start[s + 1];
    float a0 = 0.f, a1 = 0.f, a2 = 0.f, a3 = 0.f;
    for (int k = (b & ~3); k < e; k += 4) {
        uint4 ev = *(const uint4*)(edges + k);
        unsigned ed[4] = { ev.x, ev.y, ev.z, ev.w };
#pragma unroll
        for (int j = 0; j < 4; j++) {
            int kk = k + j;
            if (kk < b || kk >= e) ed[j] = 0u;
        }
        ushort4 gv[4];
#pragma unroll
        for (int j = 0; j < 4; j++) {
            gv[j] = *(const ushort4*)(E2 + (size_t)(ed[j] & 0x3FFFFu) * LATENT + 4 * l);
        }
#pragma unroll
        for (int j = 0; j < 4; j++) {
            float wv = dec_val14(ed[j] >> 18);
            const __half2* h2 = (const __half2*)&gv[j];
            a0 += wv * __low2float(h2[0]);
            a1 += wv * __high2float(h2[0]);
            a2 += wv * __low2float(h2[1]);
            a3 += wv * __high2float(h2[1]);
        }
    }
    size_t idx = (size_t)r * LATENT + 4 * l;
    float4 e0v = *(const float4*)(E0 + idx);
    ushort4 e1u = *(const ushort4*)(E1 + idx);
    ushort4 e2u = *(const ushort4*)(E2 + idx);
    const __half2* h1 = (const __half2*)&e1u;
    const __half2* h2v = (const __half2*)&e2u;
    float4 res;
    res.x = 0.25f * (e0v.x + __low2float(h1[0])  + __low2float(h2v[0])  + a0);
    res.y = 0.25f * (e0v.y + __high2float(h1[0]) + __high2float(h2v[0]) + a1);
    res.z = 0.25f * (e0v.z + __low2float(h1[1])  + __low2float(h2v[1])  + a2);
    res.w = 0.25f * (e0v.w + __high2float(h1[1]) + __high2float(h2v[1]) + a3);
    int total = nent * LATENT;
    *(float4*)(out + (size_t)i * LATENT + 4 * l) = res;
    *(float4*)(out + total + (size_t)i * LATENT + 4 * l) = e0v;
}

extern "C" void kernel_launch(void* const* d_in, const int* in_sizes, int n_in,
                              void* d_out, int out_size, void* d_ws, size_t ws_size,
                              hipStream_t stream) {
    const int*   users = (const int*)d_in[0];
    const int*   pos   = (const int*)d_in[1];
    const int*   neg   = (const int*)d_in[2];
    const float* E0    = (const float*)d_in[3];
    const int*   row   = (const int*)d_in[4];
    const int*   col   = (const int*)d_in[5];
    const float* vals  = (const float*)d_in[6];
    float*       out   = (float*)d_out;

    const int batch  = in_sizes[0];          // 4096
    const int nnz    = in_sizes[4];          // 1,200,000
    const int ntotal = in_sizes[3] / LATENT; // 150,000
    const int nbuck  = (ntotal + BROWS - 1) / BROWS;        // 2344
    const int nblkA  = (nnz + SORT_CHUNK - 1) / SORT_CHUNK; // 293

    auto align256 = [](size_t x) { return (x + 255) & ~(size_t)255; };

    const size_t hbufBytes = align256((size_t)ntotal * LATENT * sizeof(__half)); // 19.2 MB
    const size_t edgeBytes = align256((size_t)nnz * sizeof(unsigned) + 16);      // +16B uint4 slack
    const size_t auxBytes  = align256((size_t)nnz * sizeof(unsigned));           // 4.8 MB
    const size_t stBytes   = align256((size_t)(ntotal + 1) * sizeof(int));
    const size_t bsBytes   = align256((size_t)(nbuck + 1) * sizeof(int));

    char* p = (char*)d_ws;
    __half* E0h      = (__half*)p;          p += hbufBytes;
    __half* bufA     = (__half*)p;          p += hbufBytes;   // E1
    __half* bufB     = (__half*)p;          p += hbufBytes;   // E2 (csmat alias: build-only)
    __half* bufC     = (__half*)p;          p += hbufBytes;   // (aux/rowloc alias: build-only)
    unsigned* edges  = (unsigned*)p;        p += edgeBytes;   // final 4B packed edges
    int*    startA   = (int*)p;             p += stBytes;
    int*    origRow  = (int*)p;             p += stBytes;
    int*    slotOfRw = (int*)p;             p += stBytes;
    int*    bcnt     = (int*)p;             p += bsBytes;
    // aliases (consumed before their host buffers are first written):
    unsigned*      aux    = (unsigned*)bufC;
    unsigned char* rowloc = (unsigned char*)((char*)bufC + auxBytes);
    unsigned* csmat = (unsigned*)bufB;      // blk-major (blk*nbuck+b), 2.75 MB

    hipMemsetAsync(bcnt, 0, (size_t)nbuck * sizeof(int), stream);

    const int threads = 256;
    const int slotWaves = (ntotal + 7) / 8;                        // 18750 (8 slots/wave)
    const int spBlocks = (slotWaves * 64 + threads - 1) / threads; // 4688
    const int nent = 3 * batch;                                    // 12288
    const int fBlocks = (((nent + 3) / 4) * 64 + threads - 1) / threads; // 768
    const int n4 = ntotal * LATENT / 4;
    const int cBlocks4 = (n4 + SORT_T * 4 - 1) / (SORT_T * 4);     // 4 float4 per thread

    // Build degree-sorted packed CSR; conversion rides along in the same dispatch
    sortA_conv_kernel<<<nblkA + cBlocks4, SORT_T, 0, stream>>>(
        row, col, vals, aux, rowloc, csmat, bcnt, nnz, nbuck, nblkA,
        E0, E0h, n4);
    // sortB + fused layer-1 spmm (E0h -> bufA), balanced two-segment XCD swizzle
    sortB_spmm1_kernel<<<nbuck, SORT_T, 0, stream>>>(aux, rowloc, csmat, bcnt,
                                                     edges, startA, origRow, slotOfRw,
                                                     E0h, bufA,
                                                     nblkA, nbuck, ntotal, nnz);

    // Layer 2 full; layer 3 fused into finalize (batch rows only)
    spmm_slot<<<spBlocks, threads, 0, stream>>>(startA, origRow, edges, bufA, bufB, ntotal);
    fin_fused<<<fBlocks, threads, 0, stream>>>(users, pos, neg, startA, slotOfRw, edges,
                                               E0, bufA, bufB, out, batch);
}

// Round 10
// 169.648 us; speedup vs baseline: 1.1534x; 1.1534x over previous
//
#include <hip/hip_runtime.h>
#include <hip/hip_fp16.h>

#define LATENT 64
#define N_USERS_C 100000

#define BROWS 64
#define LOG_BROWS 6
#define NBUCK_MAX 2368         // >= ceil(150000/64) = 2344
#define NBLKA_MAX 512          // >= ceil(nnz/4096) = 293
#define SORT_T 256
#define SORT_E 16
#define SORT_CHUNK (SORT_T * SORT_E)   // 4096 edges per block
#define BUCK_CAP 1536          // max edges per 64-row bucket (mult of 4)

typedef unsigned short ushort8_t __attribute__((ext_vector_type(8)));

// Edge payload: col:18 | val-e4m10:14  (exp bias 0x77 -> covers 2^-8..2^7;
// vals in [0.022, 1.0]; enc==0 reserved for "zero weight").
__device__ __forceinline__ unsigned enc_val14(float v) {
    unsigned vb = (unsigned)__float_as_int(v) + 0x1000u;            // round to nearest
    return (((vb >> 23) - 0x77u) << 10) | ((vb >> 13) & 0x3FFu);    // 14 bits
}
__device__ __forceinline__ float dec_val14(unsigned m) {
    return __uint_as_float(m ? ((((m >> 10) + 0x77u) << 23) | ((m & 0x3FFu) << 13)) : 0u);
}

// ---- shfl-based scans ----
__device__ __forceinline__ int wave_iscan(int x, int lane) {
#pragma unroll
    for (int o = 1; o < 64; o <<= 1) {
        int y = __shfl_up(x, o, 64);
        if (lane >= o) x += y;
    }
    return x;   // inclusive within 64-lane wave
}
// exclusive scan of v over the 256-thread block; ws = __shared__ int[4]; *tot = grand total
__device__ __forceinline__ int block_escan(int v, int* ws, int* tot) {
    int t = threadIdx.x, lane = t & 63, w = t >> 6;
    int inc = wave_iscan(v, lane);
    __syncthreads();                 // protect ws reuse across consecutive calls
    if (lane == 63) ws[w] = inc;
    __syncthreads();
    int s0 = ws[0], s1 = ws[1], s2 = ws[2], s3 = ws[3];
    *tot = s0 + s1 + s2 + s3;
    int base = (w > 0 ? s0 : 0) + (w > 1 ? s1 : 0) + (w > 2 ? s2 : 0);
    return base + inc - v;
}

// m204 bijective XCD-contiguous swizzle WITHIN a segment of size n.
__device__ __forceinline__ int swz_seg(int i, int n) {
    const int NX = 8;
    int q = n / NX, r = n % NX;
    int x = i % NX, o = i / NX;
    return (x < r ? x * (q + 1) : r * (q + 1) + (x - r) * q) + o;
}

// ---------- Phase A: per-block LDS bucket sort (blocks [0,nblkA)) fused with
// ---------- fp32->fp16 table conversion (blocks [nblkA, ...)) ----------
// csmat is BLK-MAJOR, written in the strided (lane-coalesced) sweep.

__global__ void sortA_conv_kernel(const int* __restrict__ row, const int* __restrict__ col,
                                  const float* __restrict__ vals,
                                  unsigned* __restrict__ aux, unsigned char* __restrict__ rowloc,
                                  unsigned* __restrict__ csmat,
                                  int* __restrict__ bcnt, int nnz, int nbuck, int nblkA,
                                  const float* __restrict__ E0, __half* __restrict__ E0h,
                                  int n4) {
    __shared__ int cnt[NBUCK_MAX];
    __shared__ int off[NBUCK_MAX];
    __shared__ int ws[4];
    __shared__ unsigned buf[SORT_CHUNK];        // 16 KB
    __shared__ unsigned char rbuf[SORT_CHUNK];  // 4 KB
    int t = threadIdx.x;

    if (blockIdx.x >= nblkA) {
        // ---- conversion blocks: 4 float4 per thread, coalesced ----
        int cb = blockIdx.x - nblkA;
        int base4 = cb * (SORT_T * 4);
#pragma unroll
        for (int jj = 0; jj < 4; jj++) {
            int i = base4 + jj * SORT_T + t;
            if (i < n4) {
                float4 v = ((const float4*)E0)[i];
                __half2* o = (__half2*)E0h;
                o[2 * i]     = __floats2half2_rn(v.x, v.y);
                o[2 * i + 1] = __floats2half2_rn(v.z, v.w);
            }
        }
        return;
    }

    int blk = blockIdx.x;
    int base = blk * SORT_CHUNK;

    for (int i = t; i < nbuck; i += SORT_T) cnt[i] = 0;
    __syncthreads();

    int      eb[SORT_E];
    unsigned pl[SORT_E];
    unsigned char rl8[SORT_E];
    int quadbase = base >> 2;
#pragma unroll
    for (int jq = 0; jq < SORT_E / 4; jq++) {
        int q = quadbase + jq * SORT_T + t;      // quad index (4 edges)
        int e0 = 4 * q;
        if (e0 + 3 < nnz) {
            int4   r4 = ((const int4*)row)[q];
            int4   c4 = ((const int4*)col)[q];
            float4 v4 = ((const float4*)vals)[q];
            int   rr[4] = { r4.x, r4.y, r4.z, r4.w };
            int   cc[4] = { c4.x, c4.y, c4.z, c4.w };
            float vv[4] = { v4.x, v4.y, v4.z, v4.w };
#pragma unroll
            for (int jj = 0; jj < 4; jj++) {
                int j = 4 * jq + jj;
                int r = rr[jj];
                int b = r >> LOG_BROWS;
                eb[j] = b;
                pl[j] = (unsigned)cc[jj] | (enc_val14(vv[jj]) << 18);
                rl8[j] = (unsigned char)(r & (BROWS - 1));
                atomicAdd(&cnt[b], 1);
            }
        } else {
#pragma unroll
            for (int jj = 0; jj < 4; jj++) {
                int j = 4 * jq + jj;
                int e = e0 + jj;
                if (e < nnz) {
                    int r = row[e];
                    int b = r >> LOG_BROWS;
                    eb[j] = b;
                    pl[j] = (unsigned)col[e] | (enc_val14(vals[e]) << 18);
                    rl8[j] = (unsigned char)(r & (BROWS - 1));
                    atomicAdd(&cnt[b], 1);
                } else {
                    eb[j] = -1;
                }
            }
        }
    }
    __syncthreads();

    int chunk = (nbuck + SORT_T - 1) / SORT_T;
    int lo = t * chunk, hi = lo + chunk; if (hi > nbuck) hi = nbuck;
    int s = 0;
    for (int i = lo; i < hi; i++) s += cnt[i];
    int tot_;
    int run = block_escan(s, ws, &tot_);
    for (int i = lo; i < hi; i++) { off[i] = run; run += cnt[i]; }
    __syncthreads();

#pragma unroll
    for (int j = 0; j < SORT_E; j++) {
        if (eb[j] >= 0) {
            int p = atomicAdd(&off[eb[j]], 1);
            buf[p] = pl[j];
            rbuf[p] = rl8[j];
        }
    }
    __syncthreads();

    // strided (lane-coalesced) csmat sweep: csmat[blk * nbuck + b] = (beg<<16)|cnt
    for (int b = t; b < nbuck; b += SORT_T) {
        int c = cnt[b];
        int beg = off[b] - c;
        csmat[(size_t)blk * nbuck + b] = ((unsigned)beg << 16) | (unsigned)c;
        if (c) atomicAdd(&bcnt[b], c);
    }
    // vectorized staging writeout (uint4 / uchar4), scalar tail
    int nvalid = nnz - base; if (nvalid > SORT_CHUNK) nvalid = SORT_CHUNK;
    int nv4 = nvalid >> 2;
    for (int i = t; i < nv4; i += SORT_T) {
        *(uint4*)&aux[base + 4 * i] = *(const uint4*)&buf[4 * i];
        *(uchar4*)&rowloc[base + 4 * i] = *(const uchar4*)&rbuf[4 * i];
    }
    for (int i = (nv4 << 2) + t; i < nvalid; i += SORT_T) {
        aux[base + i] = buf[i];
        rowloc[base + i] = rbuf[i];
    }
}

// ---------- Phase B: bucket -> degree-sorted-slot CSR, FUSED with layer-1 SpMM ----
// Two-segment XCD swizzle (R8). R10: (a) placed edges also kept in LDS (plbuf)
// so the fused spmm's edge fetch is a ds_read, not an L2 round-trip on the
// dependent critical path; (b) ZIGZAG chunk pairing — wave wv handles 8-slot
// chunk wv then chunk 7-wv: balances edge load across waves while keeping
// same-degree slots within each wave (no intra-wave divergence).

__global__ void sortB_spmm1_kernel(const unsigned* __restrict__ aux,
                                   const unsigned char* __restrict__ rowloc,
                                   const unsigned* __restrict__ csmat,
                                   const int* __restrict__ bcnt,
                                   unsigned* __restrict__ edges, int* __restrict__ startOut,
                                   int* __restrict__ origRow, int* __restrict__ slotOfRow,
                                   const __half* __restrict__ E0h, __half* __restrict__ E1,
                                   int nblkA, int nbuck, int ntotal, int nnz) {
    __shared__ int rs[NBLKA_MAX], roff[NBLKA_MAX + 1];
    __shared__ int ws[4];
    __shared__ unsigned buf[BUCK_CAP];          // 6 KB (gather order)
    __shared__ unsigned plbuf[BUCK_CAP];        // 6 KB (placed order, spmm source)
    __shared__ unsigned char rbuf[BUCK_CAP];    // 1.5 KB
    __shared__ int cnt64[BROWS];
    __shared__ int slotOf[BROWS];
    __shared__ int rowOf[BROWS];
    __shared__ int offS[BROWS];
    __shared__ int placeOff[BROWS];
    __shared__ int dhist[64];
    int t = threadIdx.x;
    int lane = t & 63;

    // two-segment bijective swizzle: user segment [0,nbU), item segment [nbU,nbuck)
    int blk = blockIdx.x;
    const int nbU = (N_USERS_C + BROWS - 1) >> LOG_BROWS;   // 1563
    int b = (blk < nbU) ? swz_seg(blk, nbU)
                        : nbU + swz_seg(blk - nbU, nbuck - nbU);

    // ---- base = sum(bcnt[0..b)) via strided partials + block reduce ----
    int sb = 0;
    for (int i = t; i < b; i += SORT_T) sb += bcnt[i];
    int base;
    (void)block_escan(sb, ws, &base);      // total of partials = base

    int rbase = b * BROWS;
    int nr = ntotal - rbase; if (nr > BROWS) nr = BROWS;

    // ---- column read of blk-major csmat (L2-shared across same-XCD buckets) ----
    int chunk = (nblkA + SORT_T - 1) / SORT_T;   // 2
    int lo = t * chunk, hi = lo + chunk; if (hi > nblkA) hi = nblkA;
    int rcl[2];
    int s = 0;
    for (int i = lo; i < hi; i++) {
        unsigned v = csmat[(size_t)i * nbuck + b];
        int c = (int)(v & 0xFFFFu);
        rcl[i - lo] = c;
        rs[i] = (int)(v >> 16);
        s += c;
    }
    if (t < BROWS) cnt64[t] = 0;
    if (t < 64) dhist[t] = 0;
    int tot;                                  // bucket total = sum of chunk counts
    int run = block_escan(s, ws, &tot);
    for (int i = lo; i < hi; i++) { roff[i] = run; run += rcl[i - lo]; }
    if (t == 0) roff[nblkA] = tot;
    __syncthreads();

    // coalesced gather: edge i -> binary search run (largest with roff[r] <= i)
    for (int i = t; i < tot; i += SORT_T) {
        int lo2 = 0, hi2 = nblkA;
        while (hi2 - lo2 > 1) {
            int mid = (lo2 + hi2) >> 1;
            if (roff[mid] <= i) lo2 = mid; else hi2 = mid;
        }
        size_t src = (size_t)lo2 * SORT_CHUNK + rs[lo2] + (i - roff[lo2]);
        buf[i] = aux[src];
        unsigned char rl = rowloc[src];
        rbuf[i] = rl;
        atomicAdd(&cnt64[rl], 1);
    }
    __syncthreads();

    // ---- degree-sorted slot assignment (single-wave shfl scans) ----
    if (t < nr) { int d = min(cnt64[t], 63); atomicAdd(&dhist[d], 1); }
    __syncthreads();
    if (t < 64) {
        int x = dhist[lane];
        int inc = wave_iscan(x, lane);
        dhist[lane] = inc - x;           // exclusive
    }
    __syncthreads();
    if (t < nr) {
        int d = min(cnt64[t], 63);
        int sl = atomicAdd(&dhist[d], 1);
        slotOf[t] = sl;
        rowOf[sl] = t;
    }
    __syncthreads();
    if (t < 64) {
        int x = (lane < nr) ? cnt64[rowOf[lane]] : 0;
        int inc = wave_iscan(x, lane);
        offS[lane] = inc - x;            // exclusive
    }
    __syncthreads();

    if (t < nr) {
        startOut[rbase + t]   = base + offS[t];
        origRow[rbase + t]    = rbase + rowOf[t];
        slotOfRow[rbase + t]  = rbase + slotOf[t];   // row -> global slot (for fused L3)
        placeOff[t] = offS[slotOf[t]];
    }
    if (b == nbuck - 1 && t == 0) startOut[ntotal] = nnz;
    __syncthreads();

    // placement: fill LDS plbuf (spmm source) + global edges (layer2/fin source)
    for (int i = t; i < tot; i += SORT_T) {
        int p = atomicAdd(&placeOff[rbuf[i]], 1);
        unsigned pay = buf[i];
        plbuf[p] = pay;
        edges[base + p] = pay;
    }
    __syncthreads();   // plbuf + edges visible in-block

    // ---- fused layer-1 SpMM: zigzag chunk pairing over degree-sorted slots ----
    // 8 lanes x 8 dims per slot. Chunks of 8 adjacent (same-degree-class) slots;
    // wave wv takes chunk wv (light) then chunk 7-wv (heavy) -> balanced waves,
    // uniform trip counts within each wave.
    {
        int wv = t >> 6;
        int g = lane >> 3, l = lane & 7;
        int nc = (nr + 7) >> 3;             // chunks in this bucket (<= 8)
#pragma unroll
        for (int pass = 0; pass < 2; ++pass) {
            int c = pass ? (7 - wv) : wv;
            if (c >= nc) continue;
            int sl = 8 * c + g;
            if (sl >= nr) continue;
            int lb = offS[sl];
            int le = lb + cnt64[rowOf[sl]];
            int ro = rbase + rowOf[sl];
            float a0 = 0.f, a1 = 0.f, a2 = 0.f, a3 = 0.f;
            float a4 = 0.f, a5 = 0.f, a6 = 0.f, a7 = 0.f;
            for (int k = (lb & ~3); k < le; k += 4) {
                uint4 ev = *(const uint4*)&plbuf[k];   // LDS ds_read_b128
                unsigned ed[4] = { ev.x, ev.y, ev.z, ev.w };
#pragma unroll
                for (int j = 0; j < 4; j++) {
                    int kk = k + j;
                    if (kk < lb || kk >= le) ed[j] = 0u;   // enc==0 -> w=0, col=0
                }
                ushort8_t gv[4];
#pragma unroll
                for (int j = 0; j < 4; j++) {
                    gv[j] = *(const ushort8_t*)(E0h + (size_t)(ed[j] & 0x3FFFFu) * LATENT + 8 * l);
                }
#pragma unroll
                for (int j = 0; j < 4; j++) {
                    float wv2 = dec_val14(ed[j] >> 18);
                    const __half2* h2 = (const __half2*)&gv[j];
                    a0 += wv2 * __low2float(h2[0]);
                    a1 += wv2 * __high2float(h2[0]);
                    a2 += wv2 * __low2float(h2[1]);
                    a3 += wv2 * __high2float(h2[1]);
                    a4 += wv2 * __low2float(h2[2]);
                    a5 += wv2 * __high2float(h2[2]);
                    a6 += wv2 * __low2float(h2[3]);
                    a7 += wv2 * __high2float(h2[3]);
                }
            }
            union { ushort8_t u; __half2 h[4]; } o;
            o.h[0] = __floats2half2_rn(a0, a1);
            o.h[1] = __floats2half2_rn(a2, a3);
            o.h[2] = __floats2half2_rn(a4, a5);
            o.h[3] = __floats2half2_rn(a6, a7);
            *(ushort8_t*)(E1 + (size_t)ro * LATENT + 8 * l) = o.u;
        }
    }
}

// ---------- SpMM over degree-sorted slots (layer 2) ----------

__global__ void spmm_slot(const int* __restrict__ start, const int* __restrict__ origRow,
                          const unsigned* __restrict__ edges,
                          const __half* __restrict__ Ein, __half* __restrict__ Eout,
                          int nslots) {
    int t = blockIdx.x * blockDim.x + threadIdx.x;
    int w = t >> 6;
    int lane = t & 63;
    int g = lane >> 3, l = lane & 7;
    int s = 8 * w + g;
    if (s >= nslots) return;
    int b = start[s];
    int e = start[s + 1];
    int ro = origRow[s];
    float a0 = 0.f, a1 = 0.f, a2 = 0.f, a3 = 0.f;
    float a4 = 0.f, a5 = 0.f, a6 = 0.f, a7 = 0.f;
    for (int k = (b & ~3); k < e; k += 4) {
        uint4 ev = *(const uint4*)(edges + k);
        unsigned ed[4] = { ev.x, ev.y, ev.z, ev.w };
#pragma unroll
        for (int j = 0; j < 4; j++) {
            int kk = k + j;
            if (kk < b || kk >= e) ed[j] = 0u;   // enc==0 -> w=0, col=0
        }
        ushort8_t gv[4];
#pragma unroll
        for (int j = 0; j < 4; j++) {
            gv[j] = *(const ushort8_t*)(Ein + (size_t)(ed[j] & 0x3FFFFu) * LATENT + 8 * l);
        }
#pragma unroll
        for (int j = 0; j < 4; j++) {
            float wv = dec_val14(ed[j] >> 18);
            const __half2* h2 = (const __half2*)&gv[j];
            a0 += wv * __low2float(h2[0]);
            a1 += wv * __high2float(h2[0]);
            a2 += wv * __low2float(h2[1]);
            a3 += wv * __high2float(h2[1]);
            a4 += wv * __low2float(h2[2]);
            a5 += wv * __high2float(h2[2]);
            a6 += wv * __low2float(h2[3]);
            a7 += wv * __high2float(h2[3]);
        }
    }
    union { ushort8_t u; __half2 h[4]; } o;
    o.h[0] = __floats2half2_rn(a0, a1);
    o.h[1] = __floats2half2_rn(a2, a3);
    o.h[2] = __floats2half2_rn(a4, a5);
    o.h[3] = __floats2half2_rn(a6, a7);
    *(ushort8_t*)(Eout + (size_t)ro * LATENT + 8 * l) = o.u;
}

// ---------- Fused layer-3 + finalize ----------

__global__ void fin_fused(const int* __restrict__ users, const int* __restrict__ pos,
                          const int* __restrict__ neg,
                          const int* __restrict__ start, const int* __restrict__ slotOfRow,
                          const unsigned* __restrict__ edges,
                          const float* __restrict__ E0, const __half* __restrict__ E1,
                          const __half* __restrict__ E2,
                          float* __restrict__ out, int batch) {
    int t = blockIdx.x * blockDim.x + threadIdx.x;
    int w = t >> 6;
    int lane = t & 63;
    int g = lane >> 4, l = lane & 15;
    int i = 4 * w + g;                  // output entry 0..3*batch
    int nent = 3 * batch;
    if (i >= nent) return;
    int grp = i / batch;
    int bb = i - grp * batch;
    int r = (grp == 0) ? users[bb] : (grp == 1) ? (N_USERS_C + pos[bb]) : (N_USERS_C + neg[bb]);
    int s = slotOfRow[r];
    int b = start[s];
    int e = start[s + 1];
    float a0 = 0.f, a1 = 0.f, a2 = 0.f, a3 = 0.f;
    for (int k = (b & ~3); k < e; k += 4) {
        uint4 ev = *(const uint4*)(edges + k);
        unsigned ed[4] = { ev.x, ev.y, ev.z, ev.w };
#pragma unroll
        for (int j = 0; j < 4; j++) {
            int kk = k + j;
            if (kk < b || kk >= e) ed[j] = 0u;
        }
        ushort4 gv[4];
#pragma unroll
        for (int j = 0; j < 4; j++) {
            gv[j] = *(const ushort4*)(E2 + (size_t)(ed[j] & 0x3FFFFu) * LATENT + 4 * l);
        }
#pragma unroll
        for (int j = 0; j < 4; j++) {
            float wv = dec_val14(ed[j] >> 18);
            const __half2* h2 = (const __half2*)&gv[j];
            a0 += wv * __low2float(h2[0]);
            a1 += wv * __high2float(h2[0]);
            a2 += wv * __low2float(h2[1]);
            a3 += wv * __high2float(h2[1]);
        }
    }
    size_t idx = (size_t)r * LATENT + 4 * l;
    float4 e0v = *(const float4*)(E0 + idx);
    ushort4 e1u = *(const ushort4*)(E1 + idx);
    ushort4 e2u = *(const ushort4*)(E2 + idx);
    const __half2* h1 = (const __half2*)&e1u;
    const __half2* h2v = (const __half2*)&e2u;
    float4 res;
    res.x = 0.25f * (e0v.x + __low2float(h1[0])  + __low2float(h2v[0])  + a0);
    res.y = 0.25f * (e0v.y + __high2float(h1[0]) + __high2float(h2v[0]) + a1);
    res.z = 0.25f * (e0v.z + __low2float(h1[1])  + __low2float(h2v[1])  + a2);
    res.w = 0.25f * (e0v.w + __high2float(h1[1]) + __high2float(h2v[1]) + a3);
    int total = nent * LATENT;
    *(float4*)(out + (size_t)i * LATENT + 4 * l) = res;
    *(float4*)(out + total + (size_t)i * LATENT + 4 * l) = e0v;
}

extern "C" void kernel_launch(void* const* d_in, const int* in_sizes, int n_in,
                              void* d_out, int out_size, void* d_ws, size_t ws_size,
                              hipStream_t stream) {
    const int*   users = (const int*)d_in[0];
    const int*   pos   = (const int*)d_in[1];
    const int*   neg   = (const int*)d_in[2];
    const float* E0    = (const float*)d_in[3];
    const int*   row   = (const int*)d_in[4];
    const int*   col   = (const int*)d_in[5];
    const float* vals  = (const float*)d_in[6];
    float*       out   = (float*)d_out;

    const int batch  = in_sizes[0];          // 4096
    const int nnz    = in_sizes[4];          // 1,200,000
    const int ntotal = in_sizes[3] / LATENT; // 150,000
    const int nbuck  = (ntotal + BROWS - 1) / BROWS;        // 2344
    const int nblkA  = (nnz + SORT_CHUNK - 1) / SORT_CHUNK; // 293

    auto align256 = [](size_t x) { return (x + 255) & ~(size_t)255; };

    const size_t hbufBytes = align256((size_t)ntotal * LATENT * sizeof(__half)); // 19.2 MB
    const size_t edgeBytes = align256((size_t)nnz * sizeof(unsigned) + 16);      // +16B uint4 slack
    const size_t auxBytes  = align256((size_t)nnz * sizeof(unsigned));           // 4.8 MB
    const size_t stBytes   = align256((size_t)(ntotal + 1) * sizeof(int));
    const size_t bsBytes   = align256((size_t)(nbuck + 1) * sizeof(int));

    char* p = (char*)d_ws;
    __half* E0h      = (__half*)p;          p += hbufBytes;
    __half* bufA     = (__half*)p;          p += hbufBytes;   // E1
    __half* bufB     = (__half*)p;          p += hbufBytes;   // E2 (csmat alias: build-only)
    __half* bufC     = (__half*)p;          p += hbufBytes;   // (aux/rowloc alias: build-only)
    unsigned* edges  = (unsigned*)p;        p += edgeBytes;   // final 4B packed edges
    int*    startA   = (int*)p;             p += stBytes;
    int*    origRow  = (int*)p;             p += stBytes;
    int*    slotOfRw = (int*)p;             p += stBytes;
    int*    bcnt     = (int*)p;             p += bsBytes;
    // aliases (consumed before their host buffers are first written):
    unsigned*      aux    = (unsigned*)bufC;
    unsigned char* rowloc = (unsigned char*)((char*)bufC + auxBytes);
    unsigned* csmat = (unsigned*)bufB;      // blk-major (blk*nbuck+b), 2.75 MB

    hipMemsetAsync(bcnt, 0, (size_t)nbuck * sizeof(int), stream);

    const int threads = 256;
    const int slotWaves = (ntotal + 7) / 8;                        // 18750 (8 slots/wave)
    const int spBlocks = (slotWaves * 64 + threads - 1) / threads; // 4688
    const int nent = 3 * batch;                                    // 12288
    const int fBlocks = (((nent + 3) / 4) * 64 + threads - 1) / threads; // 768
    const int n4 = ntotal * LATENT / 4;
    const int cBlocks4 = (n4 + SORT_T * 4 - 1) / (SORT_T * 4);     // 4 float4 per thread

    // Build degree-sorted packed CSR; conversion rides along in the same dispatch
    sortA_conv_kernel<<<nblkA + cBlocks4, SORT_T, 0, stream>>>(
        row, col, vals, aux, rowloc, csmat, bcnt, nnz, nbuck, nblkA,
        E0, E0h, n4);
    // sortB + fused layer-1 spmm (E0h -> bufA), balanced two-segment XCD swizzle
    sortB_spmm1_kernel<<<nbuck, SORT_T, 0, stream>>>(aux, rowloc, csmat, bcnt,
                                                     edges, startA, origRow, slotOfRw,
                                                     E0h, bufA,
                                                     nblkA, nbuck, ntotal, nnz);

    // Layer 2 full; layer 3 fused into finalize (batch rows only)
    spmm_slot<<<spBlocks, threads, 0, stream>>>(startA, origRow, edges, bufA, bufB, ntotal);
    fin_fused<<<fBlocks, threads, 0, stream>>>(users, pos, neg, startA, slotOfRw, edges,
                                               E0, bufA, bufB, out, batch);
}

// Round 11
// 168.837 us; speedup vs baseline: 1.1590x; 1.0048x over previous
//
#include <hip/hip_runtime.h>
#include <hip/hip_fp16.h>

#define LATENT 64
#define N_USERS_C 100000

#define BROWS 64
#define LOG_BROWS 6
#define NBUCK_MAX 2368         // >= ceil(150000/64) = 2344
#define NBLKA_MAX 640          // >= ceil(nnz/2048) = 586
#define SORT_T 256
#define SORT_E 8
#define SORT_CHUNK (SORT_T * SORT_E)   // 2048 edges per block (2x blocks vs R10)
#define BUCK_CAP 1536          // fixed edge-region capacity per 64-row bucket (mult of 4)

typedef unsigned short ushort8_t __attribute__((ext_vector_type(8)));

// Edge payload: col:18 | val-e4m10:14  (exp bias 0x77 -> covers 2^-8..2^7;
// vals in [0.022, 1.0]; enc==0 reserved for "zero weight").
__device__ __forceinline__ unsigned enc_val14(float v) {
    unsigned vb = (unsigned)__float_as_int(v) + 0x1000u;            // round to nearest
    return (((vb >> 23) - 0x77u) << 10) | ((vb >> 13) & 0x3FFu);    // 14 bits
}
__device__ __forceinline__ float dec_val14(unsigned m) {
    return __uint_as_float(m ? ((((m >> 10) + 0x77u) << 23) | ((m & 0x3FFu) << 13)) : 0u);
}

// ---- shfl-based scans ----
__device__ __forceinline__ int wave_iscan(int x, int lane) {
#pragma unroll
    for (int o = 1; o < 64; o <<= 1) {
        int y = __shfl_up(x, o, 64);
        if (lane >= o) x += y;
    }
    return x;   // inclusive within 64-lane wave
}
// exclusive scan of v over the 256-thread block; ws = __shared__ int[4]; *tot = grand total
__device__ __forceinline__ int block_escan(int v, int* ws, int* tot) {
    int t = threadIdx.x, lane = t & 63, w = t >> 6;
    int inc = wave_iscan(v, lane);
    __syncthreads();                 // protect ws reuse across consecutive calls
    if (lane == 63) ws[w] = inc;
    __syncthreads();
    int s0 = ws[0], s1 = ws[1], s2 = ws[2], s3 = ws[3];
    *tot = s0 + s1 + s2 + s3;
    int base = (w > 0 ? s0 : 0) + (w > 1 ? s1 : 0) + (w > 2 ? s2 : 0);
    return base + inc - v;
}

// m204 bijective XCD-contiguous swizzle WITHIN a segment of size n.
__device__ __forceinline__ int swz_seg(int i, int n) {
    const int NX = 8;
    int q = n / NX, r = n % NX;
    int x = i % NX, o = i / NX;
    return (x < r ? x * (q + 1) : r * (q + 1) + (x - r) * q) + o;
}

// ---------- Phase A: per-block LDS bucket sort (blocks [0,nblkA)) fused with
// ---------- fp32->fp16 table conversion (blocks [nblkA, ...)) ----------
// SORT_CHUNK=2048: 586 sort blocks (~2.3/CU) and 29 KB LDS -> 2x the TLP of
// R10's grid-starved 293-block config. No bcnt: buckets own fixed regions.

__global__ void sortA_conv_kernel(const int* __restrict__ row, const int* __restrict__ col,
                                  const float* __restrict__ vals,
                                  unsigned* __restrict__ aux, unsigned char* __restrict__ rowloc,
                                  unsigned* __restrict__ csmat,
                                  int nnz, int nbuck, int nblkA,
                                  const float* __restrict__ E0, __half* __restrict__ E0h,
                                  int n4) {
    __shared__ int cnt[NBUCK_MAX];
    __shared__ int off[NBUCK_MAX];
    __shared__ int ws[4];
    __shared__ unsigned buf[SORT_CHUNK];        // 8 KB
    __shared__ unsigned char rbuf[SORT_CHUNK];  // 2 KB
    int t = threadIdx.x;

    if (blockIdx.x >= nblkA) {
        // ---- conversion blocks: 4 float4 per thread, coalesced ----
        int cb = blockIdx.x - nblkA;
        int base4 = cb * (SORT_T * 4);
#pragma unroll
        for (int jj = 0; jj < 4; jj++) {
            int i = base4 + jj * SORT_T + t;
            if (i < n4) {
                float4 v = ((const float4*)E0)[i];
                __half2* o = (__half2*)E0h;
                o[2 * i]     = __floats2half2_rn(v.x, v.y);
                o[2 * i + 1] = __floats2half2_rn(v.z, v.w);
            }
        }
        return;
    }

    int blk = blockIdx.x;
    int base = blk * SORT_CHUNK;

    for (int i = t; i < nbuck; i += SORT_T) cnt[i] = 0;
    __syncthreads();

    int      eb[SORT_E];
    unsigned pl[SORT_E];
    unsigned char rl8[SORT_E];
    int quadbase = base >> 2;
#pragma unroll
    for (int jq = 0; jq < SORT_E / 4; jq++) {
        int q = quadbase + jq * SORT_T + t;      // quad index (4 edges)
        int e0 = 4 * q;
        if (e0 + 3 < nnz) {
            int4   r4 = ((const int4*)row)[q];
            int4   c4 = ((const int4*)col)[q];
            float4 v4 = ((const float4*)vals)[q];
            int   rr[4] = { r4.x, r4.y, r4.z, r4.w };
            int   cc[4] = { c4.x, c4.y, c4.z, c4.w };
            float vv[4] = { v4.x, v4.y, v4.z, v4.w };
#pragma unroll
            for (int jj = 0; jj < 4; jj++) {
                int j = 4 * jq + jj;
                int r = rr[jj];
                int b = r >> LOG_BROWS;
                eb[j] = b;
                pl[j] = (unsigned)cc[jj] | (enc_val14(vv[jj]) << 18);
                rl8[j] = (unsigned char)(r & (BROWS - 1));
                atomicAdd(&cnt[b], 1);
            }
        } else {
#pragma unroll
            for (int jj = 0; jj < 4; jj++) {
                int j = 4 * jq + jj;
                int e = e0 + jj;
                if (e < nnz) {
                    int r = row[e];
                    int b = r >> LOG_BROWS;
                    eb[j] = b;
                    pl[j] = (unsigned)col[e] | (enc_val14(vals[e]) << 18);
                    rl8[j] = (unsigned char)(r & (BROWS - 1));
                    atomicAdd(&cnt[b], 1);
                } else {
                    eb[j] = -1;
                }
            }
        }
    }
    __syncthreads();

    int chunk = (nbuck + SORT_T - 1) / SORT_T;
    int lo = t * chunk, hi = lo + chunk; if (hi > nbuck) hi = nbuck;
    int s = 0;
    for (int i = lo; i < hi; i++) s += cnt[i];
    int tot_;
    int run = block_escan(s, ws, &tot_);
    for (int i = lo; i < hi; i++) { off[i] = run; run += cnt[i]; }
    __syncthreads();

#pragma unroll
    for (int j = 0; j < SORT_E; j++) {
        if (eb[j] >= 0) {
            int p = atomicAdd(&off[eb[j]], 1);
            buf[p] = pl[j];
            rbuf[p] = rl8[j];
        }
    }
    __syncthreads();

    // strided (lane-coalesced) csmat sweep: csmat[blk * nbuck + b] = (beg<<16)|cnt
    for (int b = t; b < nbuck; b += SORT_T) {
        int c = cnt[b];
        int beg = off[b] - c;
        csmat[(size_t)blk * nbuck + b] = ((unsigned)beg << 16) | (unsigned)c;
    }
    // vectorized staging writeout (uint4 / uchar4), scalar tail
    int nvalid = nnz - base; if (nvalid > SORT_CHUNK) nvalid = SORT_CHUNK;
    int nv4 = nvalid >> 2;
    for (int i = t; i < nv4; i += SORT_T) {
        *(uint4*)&aux[base + 4 * i] = *(const uint4*)&buf[4 * i];
        *(uchar4*)&rowloc[base + 4 * i] = *(const uchar4*)&rbuf[4 * i];
    }
    for (int i = (nv4 << 2) + t; i < nvalid; i += SORT_T) {
        aux[base + i] = buf[i];
        rowloc[base + i] = rbuf[i];
    }
}

// ---------- Phase B: bucket -> degree-sorted-slot CSR, FUSED with layer-1 SpMM ----
// Fixed-capacity regions: bucket b's edges live at [b*BUCK_CAP, ...) — no bcnt,
// no memset, no global prefix scan. Per-slot extent via cntS (start[s+1] gone).

__global__ void sortB_spmm1_kernel(const unsigned* __restrict__ aux,
                                   const unsigned char* __restrict__ rowloc,
                                   const unsigned* __restrict__ csmat,
                                   unsigned* __restrict__ edges, int* __restrict__ startOut,
                                   int* __restrict__ cntOut,
                                   int* __restrict__ origRow, int* __restrict__ slotOfRow,
                                   const __half* __restrict__ E0h, __half* __restrict__ E1,
                                   int nblkA, int nbuck, int ntotal, int nnz) {
    __shared__ int rs[NBLKA_MAX], roff[NBLKA_MAX + 1];
    __shared__ int ws[4];
    __shared__ unsigned buf[BUCK_CAP];          // 6 KB (gather order)
    __shared__ unsigned plbuf[BUCK_CAP];        // 6 KB (placed order, spmm source)
    __shared__ unsigned char rbuf[BUCK_CAP];    // 1.5 KB
    __shared__ int cnt64[BROWS];
    __shared__ int slotOf[BROWS];
    __shared__ int rowOf[BROWS];
    __shared__ int offS[BROWS];
    __shared__ int placeOff[BROWS];
    __shared__ int dhist[64];
    int t = threadIdx.x;
    int lane = t & 63;

    // two-segment bijective swizzle: user segment [0,nbU), item segment [nbU,nbuck)
    int blk = blockIdx.x;
    const int nbU = (N_USERS_C + BROWS - 1) >> LOG_BROWS;   // 1563
    int b = (blk < nbU) ? swz_seg(blk, nbU)
                        : nbU + swz_seg(blk - nbU, nbuck - nbU);

    int base = b * BUCK_CAP;               // fixed region, no global scan
    int rbase = b * BROWS;
    int nr = ntotal - rbase; if (nr > BROWS) nr = BROWS;

    // ---- column read of blk-major csmat (L2-shared across same-XCD buckets) ----
    int chunk = (nblkA + SORT_T - 1) / SORT_T;   // 3
    int lo = t * chunk, hi = lo + chunk; if (hi > nblkA) hi = nblkA;
    int rcl[4];
    int s = 0;
    for (int i = lo; i < hi; i++) {
        unsigned v = csmat[(size_t)i * nbuck + b];
        int c = (int)(v & 0xFFFFu);
        rcl[i - lo] = c;
        rs[i] = (int)(v >> 16);
        s += c;
    }
    if (t < BROWS) cnt64[t] = 0;
    if (t < 64) dhist[t] = 0;
    int tot;                                  // bucket total = sum of chunk counts
    int run = block_escan(s, ws, &tot);
    for (int i = lo; i < hi; i++) { roff[i] = run; run += rcl[i - lo]; }
    if (t == 0) roff[nblkA] = tot;
    __syncthreads();

    // coalesced gather: edge i -> binary search run (largest with roff[r] <= i)
    for (int i = t; i < tot; i += SORT_T) {
        int lo2 = 0, hi2 = nblkA;
        while (hi2 - lo2 > 1) {
            int mid = (lo2 + hi2) >> 1;
            if (roff[mid] <= i) lo2 = mid; else hi2 = mid;
        }
        size_t src = (size_t)lo2 * SORT_CHUNK + rs[lo2] + (i - roff[lo2]);
        buf[i] = aux[src];
        unsigned char rl = rowloc[src];
        rbuf[i] = rl;
        atomicAdd(&cnt64[rl], 1);
    }
    __syncthreads();

    // ---- degree-sorted slot assignment (single-wave shfl scans) ----
    if (t < nr) { int d = min(cnt64[t], 63); atomicAdd(&dhist[d], 1); }
    __syncthreads();
    if (t < 64) {
        int x = dhist[lane];
        int inc = wave_iscan(x, lane);
        dhist[lane] = inc - x;           // exclusive
    }
    __syncthreads();
    if (t < nr) {
        int d = min(cnt64[t], 63);
        int sl = atomicAdd(&dhist[d], 1);
        slotOf[t] = sl;
        rowOf[sl] = t;
    }
    __syncthreads();
    if (t < 64) {
        int x = (lane < nr) ? cnt64[rowOf[lane]] : 0;
        int inc = wave_iscan(x, lane);
        offS[lane] = inc - x;            // exclusive
    }
    __syncthreads();

    if (t < nr) {
        startOut[rbase + t]   = base + offS[t];
        cntOut[rbase + t]     = cnt64[rowOf[t]];
        origRow[rbase + t]    = rbase + rowOf[t];
        slotOfRow[rbase + t]  = rbase + slotOf[t];   // row -> global slot (for fused L3)
        placeOff[t] = offS[slotOf[t]];
    }
    __syncthreads();

    // placement: fill LDS plbuf (spmm source) + global edges (layer2/fin source)
    for (int i = t; i < tot; i += SORT_T) {
        int p = atomicAdd(&placeOff[rbuf[i]], 1);
        unsigned pay = buf[i];
        plbuf[p] = pay;
        edges[base + p] = pay;
    }
    __syncthreads();   // plbuf + edges visible in-block

    // ---- fused layer-1 SpMM: zigzag chunk pairing over degree-sorted slots ----
    {
        int wv = t >> 6;
        int g = lane >> 3, l = lane & 7;
        int nc = (nr + 7) >> 3;             // chunks in this bucket (<= 8)
#pragma unroll
        for (int pass = 0; pass < 2; ++pass) {
            int c = pass ? (7 - wv) : wv;
            if (c >= nc) continue;
            int sl = 8 * c + g;
            if (sl >= nr) continue;
            int lb = offS[sl];
            int le = lb + cnt64[rowOf[sl]];
            int ro = rbase + rowOf[sl];
            float a0 = 0.f, a1 = 0.f, a2 = 0.f, a3 = 0.f;
            float a4 = 0.f, a5 = 0.f, a6 = 0.f, a7 = 0.f;
            for (int k = (lb & ~3); k < le; k += 4) {
                uint4 ev = *(const uint4*)&plbuf[k];   // LDS ds_read_b128
                unsigned ed[4] = { ev.x, ev.y, ev.z, ev.w };
#pragma unroll
                for (int j = 0; j < 4; j++) {
                    int kk = k + j;
                    if (kk < lb || kk >= le) ed[j] = 0u;   // enc==0 -> w=0, col=0
                }
                ushort8_t gv[4];
#pragma unroll
                for (int j = 0; j < 4; j++) {
                    gv[j] = *(const ushort8_t*)(E0h + (size_t)(ed[j] & 0x3FFFFu) * LATENT + 8 * l);
                }
#pragma unroll
                for (int j = 0; j < 4; j++) {
                    float wv2 = dec_val14(ed[j] >> 18);
                    const __half2* h2 = (const __half2*)&gv[j];
                    a0 += wv2 * __low2float(h2[0]);
                    a1 += wv2 * __high2float(h2[0]);
                    a2 += wv2 * __low2float(h2[1]);
                    a3 += wv2 * __high2float(h2[1]);
                    a4 += wv2 * __low2float(h2[2]);
                    a5 += wv2 * __high2float(h2[2]);
                    a6 += wv2 * __low2float(h2[3]);
                    a7 += wv2 * __high2float(h2[3]);
                }
            }
            union { ushort8_t u; __half2 h[4]; } o;
            o.h[0] = __floats2half2_rn(a0, a1);
            o.h[1] = __floats2half2_rn(a2, a3);
            o.h[2] = __floats2half2_rn(a4, a5);
            o.h[3] = __floats2half2_rn(a6, a7);
            *(ushort8_t*)(E1 + (size_t)ro * LATENT + 8 * l) = o.u;
        }
    }
}

// ---------- SpMM over degree-sorted slots (layer 2) ----------

__global__ void spmm_slot(const int* __restrict__ start, const int* __restrict__ scnt,
                          const int* __restrict__ origRow,
                          const unsigned* __restrict__ edges,
                          const __half* __restrict__ Ein, __half* __restrict__ Eout,
                          int nslots) {
    int t = blockIdx.x * blockDim.x + threadIdx.x;
    int w = t >> 6;
    int lane = t & 63;
    int g = lane >> 3, l = lane & 7;
    int s = 8 * w + g;
    if (s >= nslots) return;
    int b = start[s];
    int e = b + scnt[s];
    int ro = origRow[s];
    float a0 = 0.f, a1 = 0.f, a2 = 0.f, a3 = 0.f;
    float a4 = 0.f, a5 = 0.f, a6 = 0.f, a7 = 0.f;
    for (int k = (b & ~3); k < e; k += 4) {
        uint4 ev = *(const uint4*)(edges + k);
        unsigned ed[4] = { ev.x, ev.y, ev.z, ev.w };
#pragma unroll
        for (int j = 0; j < 4; j++) {
            int kk = k + j;
            if (kk < b || kk >= e) ed[j] = 0u;   // enc==0 -> w=0, col=0
        }
        ushort8_t gv[4];
#pragma unroll
        for (int j = 0; j < 4; j++) {
            gv[j] = *(const ushort8_t*)(Ein + (size_t)(ed[j] & 0x3FFFFu) * LATENT + 8 * l);
        }
#pragma unroll
        for (int j = 0; j < 4; j++) {
            float wv = dec_val14(ed[j] >> 18);
            const __half2* h2 = (const __half2*)&gv[j];
            a0 += wv * __low2float(h2[0]);
            a1 += wv * __high2float(h2[0]);
            a2 += wv * __low2float(h2[1]);
            a3 += wv * __high2float(h2[1]);
            a4 += wv * __low2float(h2[2]);
            a5 += wv * __high2float(h2[2]);
            a6 += wv * __low2float(h2[3]);
            a7 += wv * __high2float(h2[3]);
        }
    }
    union { ushort8_t u; __half2 h[4]; } o;
    o.h[0] = __floats2half2_rn(a0, a1);
    o.h[1] = __floats2half2_rn(a2, a3);
    o.h[2] = __floats2half2_rn(a4, a5);
    o.h[3] = __floats2half2_rn(a6, a7);
    *(ushort8_t*)(Eout + (size_t)ro * LATENT + 8 * l) = o.u;
}

// ---------- Fused layer-3 + finalize ----------

__global__ void fin_fused(const int* __restrict__ users, const int* __restrict__ pos,
                          const int* __restrict__ neg,
                          const int* __restrict__ start, const int* __restrict__ scnt,
                          const int* __restrict__ slotOfRow,
                          const unsigned* __restrict__ edges,
                          const float* __restrict__ E0, const __half* __restrict__ E1,
                          const __half* __restrict__ E2,
                          float* __restrict__ out, int batch) {
    int t = blockIdx.x * blockDim.x + threadIdx.x;
    int w = t >> 6;
    int lane = t & 63;
    int g = lane >> 4, l = lane & 15;
    int i = 4 * w + g;                  // output entry 0..3*batch
    int nent = 3 * batch;
    if (i >= nent) return;
    int grp = i / batch;
    int bb = i - grp * batch;
    int r = (grp == 0) ? users[bb] : (grp == 1) ? (N_USERS_C + pos[bb]) : (N_USERS_C + neg[bb]);
    int s = slotOfRow[r];
    int b = start[s];
    int e = b + scnt[s];
    float a0 = 0.f, a1 = 0.f, a2 = 0.f, a3 = 0.f;
    for (int k = (b & ~3); k < e; k += 4) {
        uint4 ev = *(const uint4*)(edges + k);
        unsigned ed[4] = { ev.x, ev.y, ev.z, ev.w };
#pragma unroll
        for (int j = 0; j < 4; j++) {
            int kk = k + j;
            if (kk < b || kk >= e) ed[j] = 0u;
        }
        ushort4 gv[4];
#pragma unroll
        for (int j = 0; j < 4; j++) {
            gv[j] = *(const ushort4*)(E2 + (size_t)(ed[j] & 0x3FFFFu) * LATENT + 4 * l);
        }
#pragma unroll
        for (int j = 0; j < 4; j++) {
            float wv = dec_val14(ed[j] >> 18);
            const __half2* h2 = (const __half2*)&gv[j];
            a0 += wv * __low2float(h2[0]);
            a1 += wv * __high2float(h2[0]);
            a2 += wv * __low2float(h2[1]);
            a3 += wv * __high2float(h2[1]);
        }
    }
    size_t idx = (size_t)r * LATENT + 4 * l;
    float4 e0v = *(const float4*)(E0 + idx);
    ushort4 e1u = *(const ushort4*)(E1 + idx);
    ushort4 e2u = *(const ushort4*)(E2 + idx);
    const __half2* h1 = (const __half2*)&e1u;
    const __half2* h2v = (const __half2*)&e2u;
    float4 res;
    res.x = 0.25f * (e0v.x + __low2float(h1[0])  + __low2float(h2v[0])  + a0);
    res.y = 0.25f * (e0v.y + __high2float(h1[0]) + __high2float(h2v[0]) + a1);
    res.z = 0.25f * (e0v.z + __low2float(h1[1])  + __low2float(h2v[1])  + a2);
    res.w = 0.25f * (e0v.w + __high2float(h1[1]) + __high2float(h2v[1]) + a3);
    int total = nent * LATENT;
    *(float4*)(out + (size_t)i * LATENT + 4 * l) = res;
    *(float4*)(out + total + (size_t)i * LATENT + 4 * l) = e0v;
}

extern "C" void kernel_launch(void* const* d_in, const int* in_sizes, int n_in,
                              void* d_out, int out_size, void* d_ws, size_t ws_size,
                              hipStream_t stream) {
    const int*   users = (const int*)d_in[0];
    const int*   pos   = (const int*)d_in[1];
    const int*   neg   = (const int*)d_in[2];
    const float* E0    = (const float*)d_in[3];
    const int*   row   = (const int*)d_in[4];
    const int*   col   = (const int*)d_in[5];
    const float* vals  = (const float*)d_in[6];
    float*       out   = (float*)d_out;

    const int batch  = in_sizes[0];          // 4096
    const int nnz    = in_sizes[4];          // 1,200,000
    const int ntotal = in_sizes[3] / LATENT; // 150,000
    const int nbuck  = (ntotal + BROWS - 1) / BROWS;        // 2344
    const int nblkA  = (nnz + SORT_CHUNK - 1) / SORT_CHUNK; // 586

    auto align256 = [](size_t x) { return (x + 255) & ~(size_t)255; };

    const size_t hbufBytes = align256((size_t)ntotal * LATENT * sizeof(__half)); // 19.2 MB
    const size_t edgeBytes = align256((size_t)nbuck * BUCK_CAP * sizeof(unsigned) + 16); // 14.4 MB
    const size_t auxBytes  = align256((size_t)nnz * sizeof(unsigned));           // 4.8 MB
    const size_t stBytes   = align256((size_t)(ntotal + 1) * sizeof(int));

    char* p = (char*)d_ws;
    __half* E0h      = (__half*)p;          p += hbufBytes;
    __half* bufA     = (__half*)p;          p += hbufBytes;   // E1
    __half* bufB     = (__half*)p;          p += hbufBytes;   // E2 (csmat alias: build-only)
    __half* bufC     = (__half*)p;          p += hbufBytes;   // (aux/rowloc alias: build-only)
    unsigned* edges  = (unsigned*)p;        p += edgeBytes;   // fixed-capacity bucket regions
    int*    startA   = (int*)p;             p += stBytes;
    int*    cntS     = (int*)p;             p += stBytes;
    int*    origRow  = (int*)p;             p += stBytes;
    int*    slotOfRw = (int*)p;             p += stBytes;
    // aliases (consumed before their host buffers are first written):
    unsigned*      aux    = (unsigned*)bufC;
    unsigned char* rowloc = (unsigned char*)((char*)bufC + auxBytes);
    unsigned* csmat = (unsigned*)bufB;      // blk-major (blk*nbuck+b), 5.5 MB

    const int threads = 256;
    const int slotWaves = (ntotal + 7) / 8;                        // 18750 (8 slots/wave)
    const int spBlocks = (slotWaves * 64 + threads - 1) / threads; // 4688
    const int nent = 3 * batch;                                    // 12288
    const int fBlocks = (((nent + 3) / 4) * 64 + threads - 1) / threads; // 768
    const int n4 = ntotal * LATENT / 4;
    const int cBlocks4 = (n4 + SORT_T * 4 - 1) / (SORT_T * 4);     // 4 float4 per thread

    // Build degree-sorted packed CSR; conversion rides along in the same dispatch
    sortA_conv_kernel<<<nblkA + cBlocks4, SORT_T, 0, stream>>>(
        row, col, vals, aux, rowloc, csmat, nnz, nbuck, nblkA,
        E0, E0h, n4);
    // sortB + fused layer-1 spmm (E0h -> bufA), balanced two-segment XCD swizzle
    sortB_spmm1_kernel<<<nbuck, SORT_T, 0, stream>>>(aux, rowloc, csmat,
                                                     edges, startA, cntS, origRow, slotOfRw,
                                                     E0h, bufA,
                                                     nblkA, nbuck, ntotal, nnz);

    // Layer 2 full; layer 3 fused into finalize (batch rows only)
    spmm_slot<<<spBlocks, threads, 0, stream>>>(startA, cntS, origRow, edges, bufA, bufB, ntotal);
    fin_fused<<<fBlocks, threads, 0, stream>>>(users, pos, neg, startA, cntS, slotOfRw, edges,
                                               E0, bufA, bufB, out, batch);
}